// Round 1
// baseline (320.073 us; speedup 1.0000x reference)
//
#include <hip/hip_runtime.h>
#include <stdint.h>

// GateDotProductAttention: B=8,S=2048,D=256 fp32 in/out.
// Kernel 1: fused bidirectional flash attention (bf16 MFMA), writes fw_v/bw_v fp32 into d_out.
// Kernel 2: gate GEMMs + sigmoid blend, in-place on d_out.

typedef unsigned short u16;
typedef unsigned int u32;
typedef __attribute__((ext_vector_type(8))) short short8;   // 8 x bf16 MFMA frag
typedef __attribute__((ext_vector_type(4))) short short4v;
typedef __attribute__((ext_vector_type(4))) float f32x4;

#define B_ 8
#define S_ 2048
#define D_ 256
#define QB 64
#define KB 32
#define NT (S_/KB)

#define LOG2E 1.44269504088896340736f
#define QSCALE (LOG2E/16.0f)   // fold 1/sqrt(256) and log2(e) into Q
#define NEGM (-3.0e38f)

__device__ __forceinline__ u16 f2bf(float f) {
    union { float f; u32 u; } x; x.f = f;
    u32 u = x.u + 0x7fffu + ((x.u >> 16) & 1u);   // RNE
    return (u16)(u >> 16);
}
__device__ __forceinline__ float fget(float4 v, int i) {
    return i == 0 ? v.x : i == 1 ? v.y : i == 2 ? v.z : v.w;
}
__device__ __forceinline__ short8 pack8(float4 a, float4 b) {
    short8 r;
    r[0] = (short)f2bf(a.x); r[1] = (short)f2bf(a.y);
    r[2] = (short)f2bf(a.z); r[3] = (short)f2bf(a.w);
    r[4] = (short)f2bf(b.x); r[5] = (short)f2bf(b.y);
    r[6] = (short)f2bf(b.z); r[7] = (short)f2bf(b.w);
    return r;
}
__device__ __forceinline__ f32x4 mfma16(short8 a, short8 b, f32x4 c) {
    return __builtin_amdgcn_mfma_f32_16x16x32_bf16(a, b, c, 0, 0, 0);
}

// one direction's online-softmax + PV for the current tile.
// CMP: bw keeps j<=q ("<="), fw keeps j>=q (">=").
#define DO_DIR(CMP, mD, sD, accD)                                              \
    do {                                                                       \
        float p0_[4], p1_[4], fac_[4];                                         \
        _Pragma("unroll")                                                      \
        for (int r = 0; r < 4; ++r) {                                          \
            int qq = r0 + g * 4 + r;                                           \
            float s0 = ((j0 + c) CMP qq) ? sc0[r] : NEGM;                      \
            float s1 = ((j0 + 16 + c) CMP qq) ? sc1[r] : NEGM;                 \
            float tm = fmaxf(s0, s1);                                          \
            tm = fmaxf(tm, __shfl_xor(tm, 1));                                 \
            tm = fmaxf(tm, __shfl_xor(tm, 2));                                 \
            tm = fmaxf(tm, __shfl_xor(tm, 4));                                 \
            tm = fmaxf(tm, __shfl_xor(tm, 8));                                 \
            float mn = fmaxf(mD[r], tm);                                       \
            fac_[r] = exp2f(mD[r] - mn);                                       \
            mD[r] = mn;                                                        \
            p0_[r] = exp2f(s0 - mn);                                           \
            p1_[r] = exp2f(s1 - mn);                                           \
            float ps = p0_[r] + p1_[r];                                        \
            ps += __shfl_xor(ps, 1);                                           \
            ps += __shfl_xor(ps, 2);                                           \
            ps += __shfl_xor(ps, 4);                                           \
            ps += __shfl_xor(ps, 8);                                           \
            sD[r] = sD[r] * fac_[r] + ps;                                      \
        }                                                                      \
        _Pragma("unroll")                                                      \
        for (int r = 0; r < 4; ++r) {                                          \
            plds[wv][(g * 4 + r) * 40 + c]      = f2bf(p0_[r]);                \
            plds[wv][(g * 4 + r) * 40 + 16 + c] = f2bf(p1_[r]);                \
        }                                                                      \
        _Pragma("unroll")                                                      \
        for (int db = 0; db < 16; ++db) {                                      \
            _Pragma("unroll")                                                  \
            for (int r = 0; r < 4; ++r) accD[db][r] *= fac_[r];                \
        }                                                                      \
        short8 pa = *(const short8*)&plds[wv][c * 40 + g * 8];                 \
        _Pragma("unroll")                                                      \
        for (int db = 0; db < 16; ++db) {                                      \
            short8 vb = *(const short8*)&vtbuf[cur][(db * 16 + c) * 40 + g * 8];\
            accD[db] = mfma16(pa, vb, accD[db]);                               \
        }                                                                      \
    } while (0)

__global__ __launch_bounds__(256, 1)
void attn_kernel(const float* __restrict__ q, const float* __restrict__ k,
                 const float* __restrict__ v, float* __restrict__ out)
{
    __shared__ u16 kbuf[2][32 * 256];    // bf16, XOR-swizzled rows (16KB x2)
    __shared__ u16 vtbuf[2][256 * 40];   // bf16 V^T, padded 40 (20KB x2)
    __shared__ u16 plds[4][16 * 40];     // per-wave P round-trip

    const int tid = (int)threadIdx.x;
    const int wv = tid >> 6, lane = tid & 63;
    const int g = lane >> 4, c = lane & 15;
    const int bid = (int)blockIdx.x;
    const int b = bid & 7, qi = bid >> 3;   // batch -> XCD affinity (K/V L2-resident)
    const int q0 = qi * QB;
    const int r0 = q0 + wv * 16;

    const float* kbase = k + (size_t)b * S_ * D_;
    const float* vbase = v + (size_t)b * S_ * D_;

    // Q A-frags, pre-scaled by log2e/16
    short8 qf[8];
    {
        const float* qp = q + ((size_t)b * S_ + (size_t)(r0 + c)) * D_;
        #pragma unroll
        for (int ks = 0; ks < 8; ++ks) {
            float4 a = *(const float4*)(qp + ks * 32 + g * 8);
            float4 d = *(const float4*)(qp + ks * 32 + g * 8 + 4);
            a.x *= QSCALE; a.y *= QSCALE; a.z *= QSCALE; a.w *= QSCALE;
            d.x *= QSCALE; d.y *= QSCALE; d.z *= QSCALE; d.w *= QSCALE;
            qf[ks] = pack8(a, d);
        }
    }

    const f32x4 zero4 = {0.f, 0.f, 0.f, 0.f};
    f32x4 accF[16], accB[16];
    #pragma unroll
    for (int i = 0; i < 16; ++i) { accF[i] = zero4; accB[i] = zero4; }
    float mF[4] = {NEGM, NEGM, NEGM, NEGM}, mB[4] = {NEGM, NEGM, NEGM, NEGM};
    float sF[4] = {0.f, 0.f, 0.f, 0.f}, sB[4] = {0.f, 0.f, 0.f, 0.f};

    const int krow = tid >> 3, kcol0 = (tid & 7) * 32;
    const int vcp = tid & 63, vrp0 = tid >> 6;
    const int swz = (c & 7) << 4;

    // ---- stage tile 0 ----
    {
        #pragma unroll
        for (int cc = 0; cc < 4; ++cc) {
            float4 a = *(const float4*)(kbase + (size_t)krow * D_ + kcol0 + cc * 8);
            float4 d = *(const float4*)(kbase + (size_t)krow * D_ + kcol0 + cc * 8 + 4);
            int inner = (kcol0 * 2 + cc * 16) ^ ((krow & 7) << 4);
            *(short8*)&kbuf[0][krow * 256 + (inner >> 1)] = pack8(a, d);
        }
        #pragma unroll
        for (int pp = 0; pp < 2; ++pp) {
            int rp = vrp0 + pp * 4;
            float4 m0 = *(const float4*)(vbase + (size_t)(rp * 4 + 0) * D_ + vcp * 4);
            float4 m1 = *(const float4*)(vbase + (size_t)(rp * 4 + 1) * D_ + vcp * 4);
            float4 m2 = *(const float4*)(vbase + (size_t)(rp * 4 + 2) * D_ + vcp * 4);
            float4 m3 = *(const float4*)(vbase + (size_t)(rp * 4 + 3) * D_ + vcp * 4);
            #pragma unroll
            for (int dd = 0; dd < 4; ++dd) {
                short4v w4;
                w4[0] = (short)f2bf(fget(m0, dd));
                w4[1] = (short)f2bf(fget(m1, dd));
                w4[2] = (short)f2bf(fget(m2, dd));
                w4[3] = (short)f2bf(fget(m3, dd));
                *(short4v*)&vtbuf[0][(vcp * 4 + dd) * 40 + rp * 4] = w4;
            }
        }
    }
    __syncthreads();

    #pragma unroll 1
    for (int jt = 0; jt < NT; ++jt) {
        const int cur = jt & 1, nxt = cur ^ 1;
        const int j0 = jt * KB;
        const bool more = (jt + 1 < NT);

        // issue next tile's global loads early (hide HBM under compute)
        float4 kreg[8], vreg[8];
        if (more) {
            const float* kp = kbase + (size_t)(j0 + KB + krow) * D_ + kcol0;
            #pragma unroll
            for (int i = 0; i < 8; ++i) kreg[i] = *(const float4*)(kp + i * 4);
            const float* vp = vbase + (size_t)(j0 + KB) * D_ + vcp * 4;
            #pragma unroll
            for (int pp = 0; pp < 2; ++pp) {
                #pragma unroll
                for (int i = 0; i < 4; ++i)
                    vreg[pp * 4 + i] = *(const float4*)(vp + (size_t)((vrp0 + pp * 4) * 4 + i) * D_);
            }
        }

        // QK^T (shared by both directions)
        f32x4 sc0 = {0.f, 0.f, 0.f, 0.f}, sc1 = {0.f, 0.f, 0.f, 0.f};
        #pragma unroll
        for (int ks = 0; ks < 8; ++ks) {
            int inner = (ks * 64 + g * 16) ^ swz;
            short8 kb0 = *(const short8*)&kbuf[cur][c * 256 + (inner >> 1)];
            short8 kb1 = *(const short8*)&kbuf[cur][(16 + c) * 256 + (inner >> 1)];
            sc0 = mfma16(qf[ks], kb0, sc0);
            sc1 = mfma16(qf[ks], kb1, sc1);
        }

        const bool bwAct = (j0 <= r0 + 15);
        const bool fwAct = (j0 + KB - 1 >= r0);
        if (bwAct) DO_DIR(<=, mB, sB, accB);
        if (fwAct) DO_DIR(>=, mF, sF, accF);

        // write next tile to LDS
        if (more) {
            #pragma unroll
            for (int cc = 0; cc < 4; ++cc) {
                int inner = (kcol0 * 2 + cc * 16) ^ ((krow & 7) << 4);
                *(short8*)&kbuf[nxt][krow * 256 + (inner >> 1)] = pack8(kreg[cc * 2], kreg[cc * 2 + 1]);
            }
            #pragma unroll
            for (int pp = 0; pp < 2; ++pp) {
                int rp = vrp0 + pp * 4;
                #pragma unroll
                for (int dd = 0; dd < 4; ++dd) {
                    short4v w4;
                    w4[0] = (short)f2bf(fget(vreg[pp * 4 + 0], dd));
                    w4[1] = (short)f2bf(fget(vreg[pp * 4 + 1], dd));
                    w4[2] = (short)f2bf(fget(vreg[pp * 4 + 2], dd));
                    w4[3] = (short)f2bf(fget(vreg[pp * 4 + 3], dd));
                    *(short4v*)&vtbuf[nxt][(vcp * 4 + dd) * 40 + rp * 4] = w4;
                }
            }
        }
        __syncthreads();
    }

    // epilogue: fw_v -> out[:, :256], bw_v -> out[:, 256:]  (fp32)
    {
        float* ob = out + (size_t)b * S_ * 512;
        #pragma unroll
        for (int r = 0; r < 4; ++r) {
            int row = r0 + g * 4 + r;
            float rf = 1.0f / sF[r], rb = 1.0f / sB[r];
            float* orow = ob + (size_t)row * 512;
            #pragma unroll
            for (int db = 0; db < 16; ++db) {
                orow[db * 16 + c] = accF[db][r] * rf;
                orow[256 + db * 16 + c] = accB[db][r] * rb;
            }
        }
    }
}

__global__ __launch_bounds__(256, 1)
void gate_kernel(const float* __restrict__ v, const float* __restrict__ Wi0,
                 const float* __restrict__ Wi1, const float* __restrict__ Wo0,
                 const float* __restrict__ Wo1, const float* __restrict__ bo0,
                 const float* __restrict__ bo1, float* __restrict__ out)
{
    __shared__ u16 wlds[4][16 * 264];   // 4 mats x 16 out-cols x 256 k, padded

    const int tid = (int)threadIdx.x;
    const int wv = tid >> 6, lane = tid & 63;
    const int g = lane >> 4, c = lane & 15;
    const int t0 = (int)blockIdx.x * 64 + wv * 16;

    // A-frags: v (from input), fw_v / bw_v (from out, written by attn_kernel)
    short8 vf[8], ff[8], bf[8];
    {
        const float* vp = v + (size_t)(t0 + c) * 256;
        const float* op = out + (size_t)(t0 + c) * 512;
        #pragma unroll
        for (int ks = 0; ks < 8; ++ks) {
            int col = ks * 32 + g * 8;
            float4 a = *(const float4*)(vp + col);
            float4 b2 = *(const float4*)(vp + col + 4);
            vf[ks] = pack8(a, b2);
            a = *(const float4*)(op + col); b2 = *(const float4*)(op + col + 4);
            ff[ks] = pack8(a, b2);
            a = *(const float4*)(op + 256 + col); b2 = *(const float4*)(op + 256 + col + 4);
            bf[ks] = pack8(a, b2);
        }
    }

    const float* Wm[4] = {Wi0, Wo0, Wi1, Wo1};
    const int srow = tid >> 4;
    const int scol = (tid & 15) * 16;

    #pragma unroll 1
    for (int db = 0; db < 16; ++db) {
        __syncthreads();   // previous iteration's wlds reads done
        #pragma unroll
        for (int m = 0; m < 4; ++m) {
            const float* wp = Wm[m] + (size_t)(db * 16 + srow) * 256 + scol;
            float4 x0 = *(const float4*)(wp);
            float4 x1 = *(const float4*)(wp + 4);
            float4 x2 = *(const float4*)(wp + 8);
            float4 x3 = *(const float4*)(wp + 12);
            *(short8*)&wlds[m][srow * 264 + scol] = pack8(x0, x1);
            *(short8*)&wlds[m][srow * 264 + scol + 8] = pack8(x2, x3);
        }
        __syncthreads();

        float b0 = bo0[db * 16 + c], b1 = bo1[db * 16 + c];
        f32x4 aF = {b0, b0, b0, b0};
        f32x4 aB = {b1, b1, b1, b1};
        #pragma unroll
        for (int ks = 0; ks < 8; ++ks) {
            int off = ks * 32 + g * 8;
            short8 w0 = *(const short8*)&wlds[0][c * 264 + off];
            short8 w1 = *(const short8*)&wlds[1][c * 264 + off];
            short8 w2 = *(const short8*)&wlds[2][c * 264 + off];
            short8 w3 = *(const short8*)&wlds[3][c * 264 + off];
            aF = mfma16(vf[ks], w0, aF);
            aF = mfma16(ff[ks], w1, aF);
            aB = mfma16(vf[ks], w2, aB);
            aB = mfma16(bf[ks], w3, aB);
        }

        #pragma unroll
        for (int r = 0; r < 4; ++r) {
            int row = t0 + g * 4 + r;
            int cc = db * 16 + c;
            float vv = v[(size_t)row * 256 + cc];
            float fv = out[(size_t)row * 512 + cc];
            float bv = out[(size_t)row * 512 + 256 + cc];
            float gf = 1.0f / (1.0f + exp2f(-aF[r] * LOG2E));
            float gb = 1.0f / (1.0f + exp2f(-aB[r] * LOG2E));
            out[(size_t)row * 512 + cc] = gf * fv + (1.0f - gf) * vv;
            out[(size_t)row * 512 + 256 + cc] = gb * bv + (1.0f - gb) * vv;
        }
    }
}

extern "C" void kernel_launch(void* const* d_in, const int* in_sizes, int n_in,
                              void* d_out, int out_size, void* d_ws, size_t ws_size,
                              hipStream_t stream)
{
    const float* q   = (const float*)d_in[0];
    const float* k   = (const float*)d_in[1];
    const float* v   = (const float*)d_in[2];
    const float* Wi0 = (const float*)d_in[3];
    const float* Wi1 = (const float*)d_in[4];
    const float* Wo0 = (const float*)d_in[5];
    const float* Wo1 = (const float*)d_in[6];
    const float* bo0 = (const float*)d_in[7];
    const float* bo1 = (const float*)d_in[8];
    float* out = (float*)d_out;
    (void)in_sizes; (void)n_in; (void)d_ws; (void)ws_size; (void)out_size;

    attn_kernel<<<dim3(256), dim3(256), 0, stream>>>(q, k, v, out);
    gate_kernel<<<dim3(256), dim3(256), 0, stream>>>(v, Wi0, Wi1, Wo0, Wo1, bo0, bo1, out);
}

// Round 2
// 153.714 us; speedup vs baseline: 2.0823x; 2.0823x over previous
//
#include <hip/hip_runtime.h>
#include <stdint.h>

// GateDotProductAttention: B=8,S=2048,D=256 fp32 in/out.
// prep:  K -> bf16 swizzled LDS-image tiles, V -> V^T bf16 tiles, W -> bf16 swizzled (all in d_ws)
// attn:  fused bidirectional flash attention, no-max softmax (inputs bounded), global_load_lds staging
// gate:  gate GEMMs from pre-converted weights + sigmoid blend, in-place on d_out

typedef unsigned short u16;
typedef unsigned int u32;
typedef __attribute__((ext_vector_type(8))) short short8;
typedef __attribute__((ext_vector_type(4))) float f32x4;

#define B_ 8
#define S_ 2048
#define D_ 256
#define QB 64
#define KB 32
#define NT (S_/KB)

#define LOG2E 1.44269504088896340736f
#define QSCALE (LOG2E/16.0f)   // fold 1/sqrt(256) and log2(e) into Q

#define KSWZ_OFF 0
#define VT_OFF   (8u<<20)
#define WBF_OFF  (16u<<20)
// tile sizes: K tile 32x256 bf16 = 16384B ; V^T tile 256x32 bf16 = 16384B ; W slice 16x256 bf16 = 8192B

__device__ __forceinline__ u16 f2bf(float f) {
    union { float f; u32 u; } x; x.f = f;
    u32 u = x.u + 0x7fffu + ((x.u >> 16) & 1u);   // RNE
    return (u16)(u >> 16);
}
__device__ __forceinline__ float fget(float4 v, int i) {
    return i == 0 ? v.x : i == 1 ? v.y : i == 2 ? v.z : v.w;
}
__device__ __forceinline__ short8 pack8(float4 a, float4 b) {
    short8 r;
    r[0] = (short)f2bf(a.x); r[1] = (short)f2bf(a.y);
    r[2] = (short)f2bf(a.z); r[3] = (short)f2bf(a.w);
    r[4] = (short)f2bf(b.x); r[5] = (short)f2bf(b.y);
    r[6] = (short)f2bf(b.z); r[7] = (short)f2bf(b.w);
    return r;
}
__device__ __forceinline__ f32x4 mfma16(short8 a, short8 b, f32x4 c) {
    return __builtin_amdgcn_mfma_f32_16x16x32_bf16(a, b, c, 0, 0, 0);
}
__device__ __forceinline__ void gload_lds(const void* g, void* lds) {
    __builtin_amdgcn_global_load_lds(
        (const __attribute__((address_space(1))) void*)g,
        (__attribute__((address_space(3))) void*)lds, 16, 0, 0);
}

// ---------------------------------------------------------------- prep ----
__global__ __launch_bounds__(256, 1)
void prep_kernel(const float* __restrict__ k, const float* __restrict__ v,
                 const float* __restrict__ w0, const float* __restrict__ w1,
                 const float* __restrict__ w2, const float* __restrict__ w3,
                 char* __restrict__ ws)
{
    const int tid = (int)threadIdx.x;
    const int bid = (int)blockIdx.x;

    if (bid < 512) {
        // ---- V transpose tile: (b, jt) -> V^T [256 d][32 j] bf16
        __shared__ float vs[32][257];
        const int b = bid >> 6, jt = bid & 63;
        const float* vb = v + ((size_t)b * S_ + (size_t)jt * 32) * D_;
        const int j = tid >> 3, d0 = (tid & 7) * 32;
        #pragma unroll
        for (int i = 0; i < 8; ++i) {
            float4 x = *(const float4*)(vb + (size_t)j * D_ + d0 + i * 4);
            vs[j][d0 + i * 4 + 0] = x.x; vs[j][d0 + i * 4 + 1] = x.y;
            vs[j][d0 + i * 4 + 2] = x.z; vs[j][d0 + i * 4 + 3] = x.w;
        }
        __syncthreads();
        u16* outp = (u16*)(ws + VT_OFF) + (size_t)(b * 64 + jt) * 8192 + (size_t)tid * 32;
        short8 o[4];
        #pragma unroll
        for (int jj = 0; jj < 32; ++jj) o[jj >> 3][jj & 7] = (short)f2bf(vs[jj][tid]);
        #pragma unroll
        for (int i = 0; i < 4; ++i) *(short8*)(outp + i * 8) = o[i];
    } else if (bid < 1024) {
        // ---- K tile -> swizzled bf16 LDS image: row r, byte = r*512 + ((cg*16) ^ ((r&7)<<4))
        const int t = bid - 512, b = t >> 6, jt = t & 63;
        const float* kb = k + ((size_t)b * S_ + (size_t)jt * 32) * D_;
        char* ob = ws + KSWZ_OFF + (size_t)(b * 64 + jt) * 16384;
        #pragma unroll
        for (int it = 0; it < 4; ++it) {
            int gi = tid + it * 256;
            int r = gi >> 5, cg = gi & 31;
            float4 x0 = *(const float4*)(kb + (size_t)r * D_ + cg * 8);
            float4 x1 = *(const float4*)(kb + (size_t)r * D_ + cg * 8 + 4);
            *(short8*)(ob + r * 512 + ((cg * 16) ^ ((r & 7) << 4))) = pack8(x0, x1);
        }
    } else {
        // ---- W slice (m, db): 16 rows x 256 cols -> swizzled bf16
        const int t = bid - 1024, m = t >> 4, db = t & 15;
        const float* wsrc = (m == 0 ? w0 : m == 1 ? w1 : m == 2 ? w2 : w3)
                            + (size_t)(db * 16) * D_;
        char* ob = ws + WBF_OFF + (size_t)(m * 16 + db) * 8192;
        #pragma unroll
        for (int it = 0; it < 2; ++it) {
            int gi = tid + it * 256;
            int r = gi >> 5, cg = gi & 31;
            float4 x0 = *(const float4*)(wsrc + (size_t)r * D_ + cg * 8);
            float4 x1 = *(const float4*)(wsrc + (size_t)r * D_ + cg * 8 + 4);
            *(short8*)(ob + r * 512 + ((cg * 16) ^ ((r & 7) << 4))) = pack8(x0, x1);
        }
    }
}

// ---------------------------------------------------------------- attn ----
// PV tail shared by full/masked paths
#define PV_TAIL(accD, accS)                                                    \
    {                                                                          \
        short8 pa = *(const short8*)&plds[wv][c * 40 + g * 8];                 \
        accS = mfma16(pa, onesb, accS);                                        \
        _Pragma("unroll")                                                      \
        for (int db = 0; db < 16; ++db) {                                      \
            short8 vb = *(const short8*)((const char*)vtb[cur]                 \
                                         + (db * 16 + c) * 64 + g * 16);       \
            accD[db] = mfma16(pa, vb, accD[db]);                               \
        }                                                                      \
    }

#define DO_FULL(accD, accS)                                                    \
    {                                                                          \
        _Pragma("unroll")                                                      \
        for (int r = 0; r < 4; ++r) {                                          \
            plds[wv][(g * 4 + r) * 40 + c]      = f2bf(exp2f(sc0[r]));         \
            plds[wv][(g * 4 + r) * 40 + 16 + c] = f2bf(exp2f(sc1[r]));         \
        }                                                                      \
        PV_TAIL(accD, accS)                                                    \
    }

#define DO_MASK(CMPOP, accD, accS)                                             \
    {                                                                          \
        _Pragma("unroll")                                                      \
        for (int r = 0; r < 4; ++r) {                                          \
            int qq = r0 + g * 4 + r;                                           \
            float e0 = ((j0 + c) CMPOP qq) ? exp2f(sc0[r]) : 0.0f;             \
            float e1 = ((j0 + 16 + c) CMPOP qq) ? exp2f(sc1[r]) : 0.0f;        \
            plds[wv][(g * 4 + r) * 40 + c]      = f2bf(e0);                    \
            plds[wv][(g * 4 + r) * 40 + 16 + c] = f2bf(e1);                    \
        }                                                                      \
        PV_TAIL(accD, accS)                                                    \
    }

__global__ __launch_bounds__(256, 1)
void attn_kernel(const float* __restrict__ q, const char* __restrict__ kswz,
                 const char* __restrict__ vt, float* __restrict__ out)
{
    __shared__ u16 kbuf[2][32 * 256];   // swizzled image, 16KB each
    __shared__ u16 vtb[2][256 * 32];    // V^T [d][j], 16KB each
    __shared__ u16 plds[4][16 * 40];    // per-wave P round-trip (stride 40 keeps 16B align)

    const int tid = (int)threadIdx.x;
    const int wv = tid >> 6, lane = tid & 63;
    const int g = lane >> 4, c = lane & 15;
    const int bid = (int)blockIdx.x;
    const int b = bid & 7, qi = bid >> 3;
    const int q0 = qi * QB;
    const int r0 = q0 + wv * 16;
    const int dt = r0 >> 5;             // the single diagonal tile for this wave

    const char* kbase = kswz + (size_t)b * 64 * 16384;
    const char* vbase = vt + (size_t)b * 64 * 16384;

    // Q A-frags, pre-scaled
    short8 qf[8];
    {
        const float* qp = q + ((size_t)b * S_ + (size_t)(r0 + c)) * D_;
        #pragma unroll
        for (int ks = 0; ks < 8; ++ks) {
            float4 a = *(const float4*)(qp + ks * 32 + g * 8);
            float4 d = *(const float4*)(qp + ks * 32 + g * 8 + 4);
            a.x *= QSCALE; a.y *= QSCALE; a.z *= QSCALE; a.w *= QSCALE;
            d.x *= QSCALE; d.y *= QSCALE; d.z *= QSCALE; d.w *= QSCALE;
            qf[ks] = pack8(a, d);
        }
    }

    // ones B-frag: col 0 = 1.0 -> P @ ones = row sums in C col 0
    short8 onesb;
    #pragma unroll
    for (int i = 0; i < 8; ++i) onesb[i] = (c == 0) ? (short)0x3F80 : (short)0;

    const f32x4 zero4 = {0.f, 0.f, 0.f, 0.f};
    f32x4 accF[16], accB[16], accSF = zero4, accSB = zero4;
    #pragma unroll
    for (int i = 0; i < 16; ++i) { accF[i] = zero4; accB[i] = zero4; }

    // ---- staging: pure global_load_lds, 16B per lane, linear image copy
    #define STAGE(t, buf)                                                      \
        {                                                                      \
            const char* kg = kbase + (size_t)(t) * 16384;                      \
            const char* vg = vbase + (size_t)(t) * 16384;                      \
            _Pragma("unroll")                                                  \
            for (int i = 0; i < 4; ++i) {                                      \
                int off = i * 4096 + wv * 1024;                                \
                gload_lds(kg + off + lane * 16, (char*)kbuf[buf] + off);       \
                gload_lds(vg + off + lane * 16, (char*)vtb[buf] + off);        \
            }                                                                  \
        }

    STAGE(0, 0);
    __syncthreads();

    const int swz = (c & 7) << 4;

    #pragma unroll 1
    for (int jt = 0; jt < NT; ++jt) {
        const int cur = jt & 1;
        const int j0 = jt * KB;
        if (jt + 1 < NT) STAGE(jt + 1, cur ^ 1);

        // QK^T (shared by both directions)
        f32x4 sc0 = zero4, sc1 = zero4;
        #pragma unroll
        for (int ks = 0; ks < 8; ++ks) {
            int inner = (ks * 64 + g * 16) ^ swz;
            short8 kb0 = *(const short8*)((const char*)kbuf[cur] + c * 512 + inner);
            short8 kb1 = *(const short8*)((const char*)kbuf[cur] + (16 + c) * 512 + inner);
            sc0 = mfma16(qf[ks], kb0, sc0);
            sc1 = mfma16(qf[ks], kb1, sc1);
        }

        if (jt < dt) {
            DO_FULL(accB, accSB)            // strictly below diagonal: bw only, no mask
        } else if (jt > dt) {
            DO_FULL(accF, accSF)            // strictly above: fw only, no mask
        } else {
            DO_MASK(<=, accB, accSB)        // diagonal tile: both, masked
            DO_MASK(>=, accF, accSF)
        }
        __syncthreads();
    }

    // epilogue: normalize by MFMA-computed row sums (C col 0 lives in lane g*16)
    {
        float* ob = out + (size_t)b * S_ * 512;
        #pragma unroll
        for (int r = 0; r < 4; ++r) {
            float sf = __shfl(accSF[r], lane & 48);
            float sb = __shfl(accSB[r], lane & 48);
            float rf = 1.0f / sf, rb = 1.0f / sb;
            int row = r0 + g * 4 + r;
            float* orow = ob + (size_t)row * 512;
            #pragma unroll
            for (int db = 0; db < 16; ++db) {
                orow[db * 16 + c] = accF[db][r] * rf;
                orow[256 + db * 16 + c] = accB[db][r] * rb;
            }
        }
    }
}

// ---------------------------------------------------------------- gate ----
__global__ __launch_bounds__(256, 1)
void gate_kernel(const float* __restrict__ v, const char* __restrict__ wbf,
                 const float* __restrict__ bo0, const float* __restrict__ bo1,
                 float* __restrict__ out)
{
    __shared__ char wlds[2][4 * 8192];   // double-buffered 4-matrix slice (64KB)

    const int tid = (int)threadIdx.x;
    const int wv = tid >> 6, lane = tid & 63;
    const int g = lane >> 4, c = lane & 15;
    const int t0 = (int)blockIdx.x * 64 + wv * 16;

    // A-frags: v, fw_v, bw_v rows (fp32 -> bf16 once)
    short8 vf[8], ff[8], bf[8];
    {
        const float* vp = v + (size_t)(t0 + c) * D_;
        const float* op = out + (size_t)(t0 + c) * 512;
        #pragma unroll
        for (int ks = 0; ks < 8; ++ks) {
            int col = ks * 32 + g * 8;
            float4 a = *(const float4*)(vp + col);
            float4 b2 = *(const float4*)(vp + col + 4);
            vf[ks] = pack8(a, b2);
            a = *(const float4*)(op + col); b2 = *(const float4*)(op + col + 4);
            ff[ks] = pack8(a, b2);
            a = *(const float4*)(op + 256 + col); b2 = *(const float4*)(op + 256 + col + 4);
            bf[ks] = pack8(a, b2);
        }
    }

    #define WSTAGE(db, buf)                                                    \
        {                                                                      \
            _Pragma("unroll")                                                  \
            for (int m = 0; m < 4; ++m) {                                      \
                const char* gsrc = wbf + (size_t)(m * 16 + (db)) * 8192;       \
                _Pragma("unroll")                                              \
                for (int i = 0; i < 2; ++i) {                                  \
                    int off = i * 4096 + wv * 1024;                            \
                    gload_lds(gsrc + off + lane * 16,                          \
                              wlds[buf] + m * 8192 + off);                     \
                }                                                              \
            }                                                                  \
        }

    WSTAGE(0, 0);
    __syncthreads();

    const int swz = (c & 7) << 4;

    #pragma unroll 1
    for (int db = 0; db < 16; ++db) {
        const int cur = db & 1;
        if (db + 1 < 16) WSTAGE(db + 1, cur ^ 1);

        float b0 = bo0[db * 16 + c], b1 = bo1[db * 16 + c];
        f32x4 aF = {b0, b0, b0, b0};
        f32x4 aB = {b1, b1, b1, b1};
        #pragma unroll
        for (int ks = 0; ks < 8; ++ks) {
            int inner = (ks * 64 + g * 16) ^ swz;
            const char* base = wlds[cur] + c * 512 + inner;
            short8 w0 = *(const short8*)(base);
            short8 w1 = *(const short8*)(base + 8192);
            short8 w2 = *(const short8*)(base + 16384);
            short8 w3 = *(const short8*)(base + 24576);
            aF = mfma16(vf[ks], w0, aF);
            aF = mfma16(ff[ks], w1, aF);
            aB = mfma16(vf[ks], w2, aB);
            aB = mfma16(bf[ks], w3, aB);
        }

        #pragma unroll
        for (int r = 0; r < 4; ++r) {
            int row = t0 + g * 4 + r;
            int cc = db * 16 + c;
            float vv = v[(size_t)row * D_ + cc];
            float fv = out[(size_t)row * 512 + cc];
            float bv = out[(size_t)row * 512 + 256 + cc];
            float gf = 1.0f / (1.0f + exp2f(-aF[r] * LOG2E));
            float gb = 1.0f / (1.0f + exp2f(-aB[r] * LOG2E));
            out[(size_t)row * 512 + cc] = gf * fv + (1.0f - gf) * vv;
            out[(size_t)row * 512 + 256 + cc] = gb * bv + (1.0f - gb) * vv;
        }
        __syncthreads();
    }
}

extern "C" void kernel_launch(void* const* d_in, const int* in_sizes, int n_in,
                              void* d_out, int out_size, void* d_ws, size_t ws_size,
                              hipStream_t stream)
{
    const float* q   = (const float*)d_in[0];
    const float* k   = (const float*)d_in[1];
    const float* v   = (const float*)d_in[2];
    const float* Wi0 = (const float*)d_in[3];
    const float* Wi1 = (const float*)d_in[4];
    const float* Wo0 = (const float*)d_in[5];
    const float* Wo1 = (const float*)d_in[6];
    const float* bo0 = (const float*)d_in[7];
    const float* bo1 = (const float*)d_in[8];
    float* out = (float*)d_out;
    char* ws = (char*)d_ws;
    (void)in_sizes; (void)n_in; (void)ws_size; (void)out_size;

    // prep writes: K-swz [0,8MB), V^T [8MB,16MB), W-bf16 [16MB,16.5MB)
    prep_kernel<<<dim3(1088), dim3(256), 0, stream>>>(k, v, Wi0, Wo0, Wi1, Wo1, ws);
    attn_kernel<<<dim3(256), dim3(256), 0, stream>>>(q, ws + KSWZ_OFF, ws + VT_OFF, out);
    gate_kernel<<<dim3(256), dim3(256), 0, stream>>>(v, ws + WBF_OFF, bo0, bo1, out);
}

// Round 3
// 99.245 us; speedup vs baseline: 3.2251x; 1.5488x over previous
//
#include <hip/hip_runtime.h>
#include <stdint.h>

// GateDotProductAttention: B=8,S=2048,D=256 fp32 in/out.
// prep: K -> bf16 swizzled LDS-image tiles, V -> V^T bf16 tiles, W -> bf16 swizzled chunks (d_ws)
// attn: fused bidirectional flash attention (no-max softmax, j-split across wave halves,
//       2 waves/SIMD) + fused gate GEMMs + sigmoid blend. Single out write.

typedef unsigned short u16;
typedef unsigned int u32;
typedef __attribute__((ext_vector_type(8))) short short8;
typedef __attribute__((ext_vector_type(4))) float f32x4;

#define B_ 8
#define S_ 2048
#define D_ 256
#define QB 64
#define NP 32            // periods, 64 j-rows each

#define LOG2E 1.44269504088896340736f
#define QSCALE (LOG2E/16.0f)   // fold 1/sqrt(256) and log2(e) into Q
#define KSWZ_OFF 0
#define VT_OFF   (8u<<20)
#define WBF_OFF  (16u<<20)

__device__ __forceinline__ u16 f2bf(float f) {
    union { float f; u32 u; } x; x.f = f;
    u32 u = x.u + 0x7fffu + ((x.u >> 16) & 1u);   // RNE
    return (u16)(u >> 16);
}
__device__ __forceinline__ float fget(float4 v, int i) {
    return i == 0 ? v.x : i == 1 ? v.y : i == 2 ? v.z : v.w;
}
__device__ __forceinline__ short8 pack8(float4 a, float4 b) {
    short8 r;
    r[0] = (short)f2bf(a.x); r[1] = (short)f2bf(a.y);
    r[2] = (short)f2bf(a.z); r[3] = (short)f2bf(a.w);
    r[4] = (short)f2bf(b.x); r[5] = (short)f2bf(b.y);
    r[6] = (short)f2bf(b.z); r[7] = (short)f2bf(b.w);
    return r;
}
__device__ __forceinline__ f32x4 mfma16(short8 a, short8 b, f32x4 c) {
    return __builtin_amdgcn_mfma_f32_16x16x32_bf16(a, b, c, 0, 0, 0);
}
__device__ __forceinline__ void gload_lds(const void* g, void* lds) {
    __builtin_amdgcn_global_load_lds(
        (const __attribute__((address_space(1))) void*)g,
        (__attribute__((address_space(3))) void*)lds, 16, 0, 0);
}

// ---------------------------------------------------------------- prep ----
__global__ __launch_bounds__(256, 1)
void prep_kernel(const float* __restrict__ k, const float* __restrict__ v,
                 const float* __restrict__ w0, const float* __restrict__ w1,
                 const float* __restrict__ w2, const float* __restrict__ w3,
                 char* __restrict__ ws)
{
    const int tid = (int)threadIdx.x;
    const int bid = (int)blockIdx.x;

    if (bid < 512) {
        // ---- V transpose tile: (b, jt) -> V^T [256 d][32 j] bf16
        __shared__ float vs[32][257];
        const int b = bid >> 6, jt = bid & 63;
        const float* vb = v + ((size_t)b * S_ + (size_t)jt * 32) * D_;
        const int j = tid >> 3, d0 = (tid & 7) * 32;
        #pragma unroll
        for (int i = 0; i < 8; ++i) {
            float4 x = *(const float4*)(vb + (size_t)j * D_ + d0 + i * 4);
            vs[j][d0 + i * 4 + 0] = x.x; vs[j][d0 + i * 4 + 1] = x.y;
            vs[j][d0 + i * 4 + 2] = x.z; vs[j][d0 + i * 4 + 3] = x.w;
        }
        __syncthreads();
        u16* outp = (u16*)(ws + VT_OFF) + (size_t)(b * 64 + jt) * 8192 + (size_t)tid * 32;
        short8 o[4];
        #pragma unroll
        for (int jj = 0; jj < 32; ++jj) o[jj >> 3][jj & 7] = (short)f2bf(vs[jj][tid]);
        #pragma unroll
        for (int i = 0; i < 4; ++i) *(short8*)(outp + i * 8) = o[i];
    } else if (bid < 1024) {
        // ---- K tile -> swizzled bf16 LDS image: row r, byte = r*512 + ((cg*16) ^ ((r&7)<<4))
        const int t = bid - 512, b = t >> 6, jt = t & 63;
        const float* kb = k + ((size_t)b * S_ + (size_t)jt * 32) * D_;
        char* ob = ws + KSWZ_OFF + (size_t)(b * 64 + jt) * 16384;
        #pragma unroll
        for (int it = 0; it < 4; ++it) {
            int gi = tid + it * 256;
            int r = gi >> 5, cg = gi & 31;
            float4 x0 = *(const float4*)(kb + (size_t)r * D_ + cg * 8);
            float4 x1 = *(const float4*)(kb + (size_t)r * D_ + cg * 8 + 4);
            *(short8*)(ob + r * 512 + ((cg * 16) ^ ((r & 7) << 4))) = pack8(x0, x1);
        }
    } else {
        // ---- W slice (m, db): 16 rows x 256 cols -> swizzled bf16, chunk order (db*4+m)
        const int t = bid - 1024, m = t >> 4, db = t & 15;
        const float* wsrc = (m == 0 ? w0 : m == 1 ? w1 : m == 2 ? w2 : w3)
                            + (size_t)(db * 16) * D_;
        char* ob = ws + WBF_OFF + (size_t)(db * 4 + m) * 8192;
        #pragma unroll
        for (int it = 0; it < 2; ++it) {
            int gi = tid + it * 256;
            int r = gi >> 5, cg = gi & 31;
            float4 x0 = *(const float4*)(wsrc + (size_t)r * D_ + cg * 8);
            float4 x1 = *(const float4*)(wsrc + (size_t)r * D_ + cg * 8 + 4);
            *(short8*)(ob + r * 512 + ((cg * 16) ^ ((r & 7) << 4))) = pack8(x0, x1);
        }
    }
}

// ---------------------------------------------------------------- attn ----
#define PV_TAIL(accD, accS)                                                    \
    {                                                                          \
        short8 pa = *(const short8*)&pw[c * 40 + g * 8];                       \
        __builtin_amdgcn_s_setprio(1);                                         \
        accS = mfma16(pa, onesb, accS);                                        \
        _Pragma("unroll")                                                      \
        for (int db = 0; db < 16; ++db) {                                      \
            short8 vb = *(const short8*)(vcur + (db * 16 + c) * 64 + g * 16);  \
            accD[db] = mfma16(pa, vb, accD[db]);                               \
        }                                                                      \
        __builtin_amdgcn_s_setprio(0);                                         \
    }

#define DO_FULL(accD, accS)                                                    \
    {                                                                          \
        _Pragma("unroll")                                                      \
        for (int r = 0; r < 4; ++r) {                                          \
            pw[(g * 4 + r) * 40 + c]      = f2bf(exp2f(sc0[r]));               \
            pw[(g * 4 + r) * 40 + 16 + c] = f2bf(exp2f(sc1[r]));               \
        }                                                                      \
        PV_TAIL(accD, accS)                                                    \
    }

#define DO_MASK(CMPOP, accD, accS)                                             \
    {                                                                          \
        _Pragma("unroll")                                                      \
        for (int r = 0; r < 4; ++r) {                                          \
            int qq = r0 + g * 4 + r;                                           \
            float e0 = ((j0 + c) CMPOP qq) ? exp2f(sc0[r]) : 0.0f;             \
            float e1 = ((j0 + 16 + c) CMPOP qq) ? exp2f(sc1[r]) : 0.0f;        \
            pw[(g * 4 + r) * 40 + c]      = f2bf(e0);                          \
            pw[(g * 4 + r) * 40 + 16 + c] = f2bf(e1);                          \
        }                                                                      \
        PV_TAIL(accD, accS)                                                    \
    }

__global__ __launch_bounds__(512, 2)
void attn_kernel(const float* __restrict__ q, const char* __restrict__ kswz,
                 const char* __restrict__ vt, const char* __restrict__ wbf,
                 const float* __restrict__ v,
                 const float* __restrict__ bo0, const float* __restrict__ bo1,
                 float* __restrict__ out)
{
    // LDS map: [0,64KB) K dbuf / merge-F / att image ; [64KB,128KB) V^T dbuf / merge-B / W dbuf
    //          [128KB,138KB) per-wave P ; sums overlap P area in epilogue
    __shared__ char smem[141824];
    u16* kbL = (u16*)smem;
    char* vtA = smem + 65536;
    u16* pl = (u16*)(smem + 131072);

    const int tid = (int)threadIdx.x;
    const int wv = tid >> 6, lane = tid & 63;
    const int h = wv >> 2, wl = wv & 3;
    const int g = lane >> 4, c = lane & 15;
    const int bid = (int)blockIdx.x;
    const int b = bid & 7, qi = bid >> 3;
    const int q0 = qi * QB;
    const int r0 = q0 + wl * 16;            // global q row base of this wave
    const int dt = r0 >> 5;                 // diagonal 32-j-block index
    u16* pw = pl + wv * 640;

    const char* kbase = kswz + (size_t)b * (64 * 16384);
    const char* vbase = vt + (size_t)b * (64 * 16384);

    // Q A-frags (pre-scaled)
    short8 qf[8];
    {
        const float* qp = q + ((size_t)b * S_ + (size_t)(r0 + c)) * D_;
        #pragma unroll
        for (int ks = 0; ks < 8; ++ks) {
            float4 a = *(const float4*)(qp + ks * 32 + g * 8);
            float4 d = *(const float4*)(qp + ks * 32 + g * 8 + 4);
            a.x *= QSCALE; a.y *= QSCALE; a.z *= QSCALE; a.w *= QSCALE;
            d.x *= QSCALE; d.y *= QSCALE; d.z *= QSCALE; d.w *= QSCALE;
            qf[ks] = pack8(a, d);
        }
    }

    short8 onesb;
    #pragma unroll
    for (int i = 0; i < 8; ++i) onesb[i] = (c == 0) ? (short)0x3F80 : (short)0;

    const f32x4 zero4 = {0.f, 0.f, 0.f, 0.f};
    f32x4 accF[16], accB[16], accSF = zero4, accSB = zero4;
    #pragma unroll
    for (int i = 0; i < 16; ++i) { accF[i] = zero4; accB[i] = zero4; }

    // stage one 64-row period (32KB K + 32KB V^T), linear copy
    #define STAGE(t, buf)                                                      \
        {                                                                      \
            const char* kg = kbase + (size_t)(t) * 32768;                      \
            const char* vg = vbase + (size_t)(t) * 32768;                      \
            _Pragma("unroll")                                                  \
            for (int i = 0; i < 4; ++i) {                                      \
                int off = i * 8192 + wv * 1024;                                \
                gload_lds(kg + off + lane * 16, (char*)kbL + (buf) * 32768 + off); \
                gload_lds(vg + off + lane * 16, vtA + (buf) * 32768 + off);    \
            }                                                                  \
        }

    STAGE(0, 0);
    __syncthreads();

    const int swz = (c & 7) << 4;

    #pragma unroll 1
    for (int t = 0; t < NP; ++t) {
        const int cur = t & 1;
        if (t + 1 < NP) STAGE(t + 1, cur ^ 1);

        const int jw = 2 * t + h;           // this wave's 32-j block index
        const int j0 = jw * 32;
        const char* kcur = (const char*)kbL + cur * 32768 + h * 16384;
        const char* vcur = vtA + cur * 32768 + h * 16384;

        f32x4 sc0 = zero4, sc1 = zero4;
        __builtin_amdgcn_s_setprio(1);
        #pragma unroll
        for (int ks = 0; ks < 8; ++ks) {
            int inner = (ks * 64 + g * 16) ^ swz;
            short8 kb0 = *(const short8*)(kcur + c * 512 + inner);
            short8 kb1 = *(const short8*)(kcur + (16 + c) * 512 + inner);
            sc0 = mfma16(qf[ks], kb0, sc0);
            sc1 = mfma16(qf[ks], kb1, sc1);
        }
        __builtin_amdgcn_s_setprio(0);

        if (jw < dt) {
            DO_FULL(accB, accSB)
        } else if (jw > dt) {
            DO_FULL(accF, accSF)
        } else {
            DO_MASK(<=, accB, accSB)
            DO_MASK(>=, accF, accSF)
        }
        __syncthreads();
    }

    // ---- epilogue: merge halves, then fused gate ----
    float* sumsA = (float*)(smem + 131072);        // sF partial from half1 (64)
    float* sumsB = (float*)(smem + 131072 + 256);  // sB partial from half0 (64)

    // P0: exchange partials (half1 -> accF region [0,64KB), half0 -> accB region [64,128KB))
    if (h == 1) {
        float* dst = (float*)smem + wl * 4096;
        #pragma unroll
        for (int db = 0; db < 16; ++db)
            #pragma unroll
            for (int r = 0; r < 4; ++r)
                dst[(g * 4 + r) * 256 + db * 16 + c] = accF[db][r];
        if (c == 0) {
            #pragma unroll
            for (int r = 0; r < 4; ++r) sumsA[wl * 16 + g * 4 + r] = accSF[r];
        }
    } else {
        float* dst = (float*)vtA + wl * 4096;
        #pragma unroll
        for (int db = 0; db < 16; ++db)
            #pragma unroll
            for (int r = 0; r < 4; ++r)
                dst[(g * 4 + r) * 256 + db * 16 + c] = accB[db][r];
        if (c == 0) {
            #pragma unroll
            for (int r = 0; r < 4; ++r) sumsB[wl * 16 + g * 4 + r] = accSB[r];
        }
    }
    __syncthreads();

    // P1: merge + normalize. half0 owns fw rows, half1 owns bw rows.
    f32x4 merged[16];
    if (h == 0) {
        const float* src = (const float*)smem + wl * 4096;
        float rs[4];
        #pragma unroll
        for (int r = 0; r < 4; ++r) {
            float so = __shfl(accSF[r], lane & 48);
            rs[r] = 1.0f / (so + sumsA[wl * 16 + g * 4 + r]);
        }
        #pragma unroll
        for (int db = 0; db < 16; ++db)
            #pragma unroll
            for (int r = 0; r < 4; ++r)
                merged[db][r] = (accF[db][r] + src[(g * 4 + r) * 256 + db * 16 + c]) * rs[r];
    } else {
        const float* src = (const float*)vtA + wl * 4096;
        float rs[4];
        #pragma unroll
        for (int r = 0; r < 4; ++r) {
            float so = __shfl(accSB[r], lane & 48);
            rs[r] = 1.0f / (so + sumsB[wl * 16 + g * 4 + r]);
        }
        #pragma unroll
        for (int db = 0; db < 16; ++db)
            #pragma unroll
            for (int r = 0; r < 4; ++r)
                merged[db][r] = (accB[db][r] + src[(g * 4 + r) * 256 + db * 16 + c]) * rs[r];
    }
    __syncthreads();

    // P2: write att_v bf16 swizzled image (h0: fw @ [0,32KB), h1: bw @ [32,64KB)) + stage W chunk 0
    {
        char* imgb = smem + h * 32768;
        #pragma unroll
        for (int db = 0; db < 16; ++db)
            #pragma unroll
            for (int r = 0; r < 4; ++r) {
                int lr = wl * 16 + g * 4 + r;
                int cb = (db * 16 + c) * 2;
                *(u16*)(imgb + lr * 512 + (cb ^ ((lr & 7) << 4))) = f2bf(merged[db][r]);
            }
    }
    #define WSTAGE(db, buf)                                                    \
        {                                                                      \
            const char* gsrc = wbf + (size_t)(db) * 32768;                     \
            _Pragma("unroll")                                                  \
            for (int i = 0; i < 4; ++i) {                                      \
                int off = i * 8192 + wv * 1024;                                \
                gload_lds(gsrc + off + lane * 16, vtA + (buf) * 32768 + off);  \
            }                                                                  \
        }
    WSTAGE(0, 0);
    __syncthreads();

    // P3: A-frags for own direction (att image) and v (global)
    short8 af[8], vf[8];
    {
        const char* imgb = smem + h * 32768;
        int lr = wl * 16 + c;
        #pragma unroll
        for (int ks = 0; ks < 8; ++ks) {
            int inner = (ks * 64 + g * 16) ^ swz;
            af[ks] = *(const short8*)(imgb + lr * 512 + inner);
        }
        const float* vp = v + ((size_t)b * S_ + (size_t)(r0 + c)) * D_;
        #pragma unroll
        for (int ks = 0; ks < 8; ++ks) {
            float4 a = *(const float4*)(vp + ks * 32 + g * 8);
            float4 d = *(const float4*)(vp + ks * 32 + g * 8 + 4);
            vf[ks] = pack8(a, d);
        }
    }

    // db loop: gate GEMM (own direction) + blend + store. Fully unrolled (static merged idx).
    const float* bias = (h == 0) ? bo0 : bo1;
    const float* vrow = v + ((size_t)b * S_ + (size_t)r0) * D_;
    float* ob = out + ((size_t)b * S_ + (size_t)r0) * 512 + h * 256;
    #pragma unroll
    for (int db = 0; db < 16; ++db) {
        const int cu2 = db & 1;
        if (db + 1 < 16) WSTAGE(db + 1, cu2 ^ 1);

        float bb = bias[db * 16 + c];
        f32x4 a = {bb, bb, bb, bb};
        const char* wc = vtA + cu2 * 32768 + h * 16384;
        __builtin_amdgcn_s_setprio(1);
        #pragma unroll
        for (int ks = 0; ks < 8; ++ks) {
            int inner = (ks * 64 + g * 16) ^ swz;
            short8 wi = *(const short8*)(wc + c * 512 + inner);
            short8 wo = *(const short8*)(wc + 8192 + c * 512 + inner);
            a = mfma16(vf[ks], wi, a);
            a = mfma16(af[ks], wo, a);
        }
        __builtin_amdgcn_s_setprio(0);

        #pragma unroll
        for (int r = 0; r < 4; ++r) {
            int row = g * 4 + r;
            float vv = vrow[(size_t)row * D_ + db * 16 + c];
            float gate = 1.0f / (1.0f + exp2f(-a[r] * LOG2E));
            float m = merged[db][r];
            ob[(size_t)row * 512 + db * 16 + c] = gate * m + (1.0f - gate) * vv;
        }
        __syncthreads();
    }
}

extern "C" void kernel_launch(void* const* d_in, const int* in_sizes, int n_in,
                              void* d_out, int out_size, void* d_ws, size_t ws_size,
                              hipStream_t stream)
{
    const float* q   = (const float*)d_in[0];
    const float* k   = (const float*)d_in[1];
    const float* v   = (const float*)d_in[2];
    const float* Wi0 = (const float*)d_in[3];
    const float* Wi1 = (const float*)d_in[4];
    const float* Wo0 = (const float*)d_in[5];
    const float* Wo1 = (const float*)d_in[6];
    const float* bo0 = (const float*)d_in[7];
    const float* bo1 = (const float*)d_in[8];
    float* out = (float*)d_out;
    char* ws = (char*)d_ws;
    (void)in_sizes; (void)n_in; (void)ws_size; (void)out_size;

    // prep: K-swz [0,8MB), V^T [8MB,16MB), W-bf16 chunks [16MB,16.5MB)
    prep_kernel<<<dim3(1088), dim3(256), 0, stream>>>(k, v, Wi0, Wo0, Wi1, Wo1, ws);
    attn_kernel<<<dim3(256), dim3(512), 0, stream>>>(q, ws + KSWZ_OFF, ws + VT_OFF,
                                                     ws + WBF_OFF, v, bo0, bo1, out);
}